// Round 22
// baseline (288.592 us; speedup 1.0000x reference)
//
#include <hip/hip_runtime.h>

#define S 2048
#define H 1024
#define NH 16
#define NKV 8
#define HD 64
#define NE 8
#define ID 2048

typedef short bf16x8 __attribute__((ext_vector_type(8)));
typedef short bf16x4 __attribute__((ext_vector_type(4)));
typedef float f32x4 __attribute__((ext_vector_type(4)));

__device__ __forceinline__ unsigned short f2bf(float f) {
  unsigned u = __builtin_bit_cast(unsigned, f);
  u += 0x7FFFu + ((u >> 16) & 1u);
  return (unsigned short)(u >> 16);
}
__device__ __forceinline__ float bf2f(unsigned short h) {
  unsigned u = ((unsigned)h) << 16;
  return __builtin_bit_cast(float, u);
}
// packed f32x2 -> bf16x2; rounding differences vs f2bf absorbed by lo residual.
__device__ __forceinline__ unsigned cvtpk(float a, float b) {
  unsigned r;
  asm("v_cvt_pk_bf16_f32 %0, %1, %2" : "=v"(r) : "v"(a), "v"(b));
  return r;
}

typedef const __attribute__((address_space(1))) unsigned int gas_u32;
typedef __attribute__((address_space(3))) unsigned int las_u32;
__device__ __forceinline__ void gload16(const unsigned short* g, unsigned short* l) {
  __builtin_amdgcn_global_load_lds((gas_u32*)g, (las_u32*)l, 16, 0, 0);
}

// ---------------- shared tconv body: one 128k x 64n tile, f32 [K][N] -> bf16 [N][K] --------
template <bool LO>
__device__ __forceinline__ void tconv_tile128(const float* __restrict__ src,
                                              unsigned short* __restrict__ hi,
                                              unsigned short* __restrict__ lo, int K, int N,
                                              int nt, int kt, float (*tile)[65]) {
  int tid = threadIdx.x;
  int wv = tid >> 6, ln = tid & 63;
  const float* sb = src + (size_t)(kt * 128) * N + nt * 64 + ln;
#pragma unroll 8
  for (int rr = 0; rr < 32; rr++) {
    int r = rr * 4 + wv;
    tile[r][ln] = sb[(size_t)r * N];
  }
  __syncthreads();
  int seg = tid & 15;  // 16 segs x 8 cols
  int rq = tid >> 4;   // 0..15
#pragma unroll
  for (int it = 0; it < 4; it++) {
    int row = it * 16 + rq;
    int cs = seg * 8;
    size_t dbase = (size_t)(nt * 64 + row) * K + kt * 128 + cs;
    unsigned short th[8], tl[8];
#pragma unroll
    for (int i = 0; i < 8; i++) {
      float vv = tile[cs + i][row];
      unsigned short h_ = f2bf(vv);
      th[i] = h_;
      if (LO) tl[i] = f2bf(vv - bf2f(h_));
    }
    *(bf16x8*)(hi + dbase) = *(bf16x8*)&th[0];
    if (LO) *(bf16x8*)(lo + dbase) = *(bf16x8*)&tl[0];
  }
}

// ---------------- prep: rmsnorm(ln1) + attn-weight tconv, ONE launch ----------------
__global__ __launch_bounds__(256) void prep_kernel(
    const float* __restrict__ x, const float* __restrict__ ln1,
    unsigned short* __restrict__ h_hi, unsigned short* __restrict__ h_lo,
    const float* __restrict__ wq, const float* __restrict__ wk, const float* __restrict__ wv,
    const float* __restrict__ wo, unsigned short* __restrict__ wqkvT_hi,
    unsigned short* __restrict__ wqkvT_lo, unsigned short* __restrict__ woT_hi,
    unsigned short* __restrict__ woT_lo) {
  __shared__ float tile[128][65];
  __shared__ float part[4];
  int u = blockIdx.x, grp = u / 19, slot = u % 19;
  int tid = threadIdx.x;
  if (slot < 16) {
    int row = grp * 16 + slot;
    const float* xr = x + (size_t)row * H;
    float v[4];
    float ss = 0.f;
#pragma unroll
    for (int i = 0; i < 4; i++) {
      v[i] = xr[tid + i * 256];
      ss += v[i] * v[i];
    }
#pragma unroll
    for (int off = 1; off < 64; off <<= 1) ss += __shfl_xor(ss, off);
    if ((tid & 63) == 0) part[tid >> 6] = ss;
    __syncthreads();
    float tot = part[0] + part[1] + part[2] + part[3];
    float r = rsqrtf(tot * (1.f / H) + 1e-6f);
#pragma unroll
    for (int i = 0; i < 4; i++) {
      int c = tid + i * 256;
      float vv = v[i] * r * ln1[c];
      size_t o = (size_t)row * H + c;
      unsigned short h_ = f2bf(vv);
      h_hi[o] = h_;
      h_lo[o] = f2bf(vv - bf2f(h_));
    }
  } else {
    int local = grp * 3 + (slot - 16);
    const float* src;
    unsigned short *hi, *lo;
    int N, l2;
    if (local < 128) {
      src = wq; hi = wqkvT_hi; lo = wqkvT_lo; N = 1024; l2 = local;
    } else if (local < 192) {
      src = wk; hi = wqkvT_hi + (size_t)1024 * 1024; lo = wqkvT_lo + (size_t)1024 * 1024; N = 512; l2 = local - 128;
    } else if (local < 256) {
      src = wv; hi = wqkvT_hi + (size_t)1536 * 1024; lo = wqkvT_lo + (size_t)1536 * 1024; N = 512; l2 = local - 192;
    } else {
      src = wo; hi = woT_hi; lo = woT_lo; N = 1024; l2 = local - 256;
    }
    int ntc = N >> 6;
    int nt = l2 % ntc, kt = l2 / ntc;
    tconv_tile128<true>(src, hi, lo, 1024, N, nt, kt, tile);
  }
}

// ---------------- rv: rope + vtrans, ONE launch (6400 blocks, u%25==0 -> vtrans) ----------
__global__ __launch_bounds__(256) void rv_kernel(
    const float* __restrict__ qkv, const float* __restrict__ sinb,
    const float* __restrict__ cosb, const int* __restrict__ pos,
    unsigned short* __restrict__ qhi, unsigned short* __restrict__ qlo,
    unsigned short* __restrict__ khi, unsigned short* __restrict__ klo,
    unsigned short* __restrict__ vThi, unsigned short* __restrict__ vTlo) {
  __shared__ float tile[64][65];
  int u = blockIdx.x, grp = u / 25, slot = u % 25;
  int tid = threadIdx.x;
  if (slot == 0) {
    int st = grp & 31, hk = grp >> 5;
    int r = tid >> 2, seg = (tid & 3) * 16;
    const float* src = qkv + (size_t)(st * 64 + r) * 2048 + 1536 + hk * HD + seg;
#pragma unroll
    for (int i = 0; i < 16; i += 4) {
      float4 a = *(const float4*)(src + i);
      tile[r][seg + i] = a.x;
      tile[r][seg + i + 1] = a.y;
      tile[r][seg + i + 2] = a.z;
      tile[r][seg + i + 3] = a.w;
    }
    __syncthreads();
    int d = tid >> 2, ss = (tid & 3) * 16;
    unsigned short th[16], tl[16];
#pragma unroll
    for (int i = 0; i < 16; i++) {
      float vv = tile[ss + i][d];
      unsigned short h_ = f2bf(vv);
      th[i] = h_;
      tl[i] = f2bf(vv - bf2f(h_));
    }
    size_t dst = ((size_t)hk * HD + d) * S + st * 64 + ss;
    *(bf16x8*)(vThi + dst) = *(bf16x8*)&th[0];
    *(bf16x8*)(vThi + dst + 8) = *(bf16x8*)&th[8];
    *(bf16x8*)(vTlo + dst) = *(bf16x8*)&tl[0];
    *(bf16x8*)(vTlo + dst + 8) = *(bf16x8*)&tl[8];
  } else {
    int i = (grp * 24 + slot - 1) * 256 + tid;
    int d = i & 31;
    int s = (i >> 5) & 2047;
    int hh = i >> 16;  // 0..23
    int p = pos[s];
    float c0 = cosb[p * HD + d], c1 = cosb[p * HD + d + 32];
    float s0 = sinb[p * HD + d], s1 = sinb[p * HD + d + 32];
    const float* srcb = qkv + (size_t)s * 2048;
    if (hh < NH) {
      float x0 = srcb[hh * HD + d], x1 = srcb[hh * HD + d + 32];
      float r0 = (x0 * c0 - x1 * s0) * 0.125f;
      float r1 = (x1 * c1 + x0 * s1) * 0.125f;
      size_t o = ((size_t)hh * S + s) * HD + d;
      unsigned short h0 = f2bf(r0), h1 = f2bf(r1);
      qhi[o] = h0;
      qlo[o] = f2bf(r0 - bf2f(h0));
      qhi[o + 32] = h1;
      qlo[o + 32] = f2bf(r1 - bf2f(h1));
    } else {
      int hk = hh - NH;
      float x0 = srcb[1024 + hk * HD + d], x1 = srcb[1024 + hk * HD + d + 32];
      float r0 = x0 * c0 - x1 * s0;
      float r1 = x1 * c1 + x0 * s1;
      size_t o = ((size_t)hk * S + s) * HD + d;
      unsigned short h0 = f2bf(r0), h1 = f2bf(r1);
      khi[o] = h0;
      klo[o] = f2bf(r0 - bf2f(h0));
      khi[o + 32] = h1;
      klo[o + 32] = f2bf(r1 - bf2f(h1));
    }
  }
}

// ---------------- merged flash attention + w1/w3 tconv (co-scheduled, 5120 blocks) --------
// u%5==0 -> flash block (1024, balanced decode); else w13 tconv tile (4096).
// Flash: latency-bound (1.2 TB/s, 19% MFMA) hides w13's pure memory traffic.
#define FSWZ(row, byteoff) ((byteoff) ^ (((row) & 7) << 4))

__global__ __launch_bounds__(256, 4) void flash_w13_kernel(
    const unsigned short* __restrict__ qhi, const unsigned short* __restrict__ qlo,
    const unsigned short* __restrict__ khip, const unsigned short* __restrict__ klop,
    const unsigned short* __restrict__ vthip, const unsigned short* __restrict__ vtlop,
    const float* __restrict__ amask, float* __restrict__ po, float* __restrict__ pm,
    float* __restrict__ pl, const float* __restrict__ w1, const float* __restrict__ w3,
    unsigned short* __restrict__ w1T, unsigned short* __restrict__ w3T) {
  __shared__ __align__(16) char smem[40960];
  int uu = blockIdx.x, grp = uu / 5, slot = uu % 5;
  int tid = threadIdx.x;
  if (slot != 0) {
    int t = grp * 4 + slot - 1;  // 0..4095
    int b = t >> 8, rem = t & 255, kt = rem >> 5, nt = rem & 31;
    const float* src = (b < 8) ? w1 + (size_t)b * 1024 * 2048 : w3 + (size_t)(b - 8) * 1024 * 2048;
    unsigned short* hi = (b < 8) ? w1T + (size_t)b * 2048 * 1024 : w3T + (size_t)(b - 8) * 2048 * 1024;
    tconv_tile128<false>(src, hi, nullptr, 1024, 2048, nt, kt, (float(*)[65])smem);
    return;
  }
  // ---- flash block ----
  unsigned short* Khi = (unsigned short*)smem;
  unsigned short* Klo = Khi + 4096;
  unsigned short* Vhi = Klo + 4096;
  unsigned short* Vlo = Vhi + 4096;
  unsigned short* Pbuf = Vlo + 4096;  // 4 waves x 1024 u16
  int u = grp;
  int r_ = u >> 8, base = u & 255;
  int qt = (base + r_ * 8) & 31;
  int head = ((base >> 5) & 7) | ((r_ & 1) << 3);
  int z = r_ >> 1;
  int w = tid >> 6, lane = tid & 63;
  int lr = lane & 15, g = lane >> 4;
  int rloc = lane >> 3, slotg = (lane & 7) ^ rloc;

  int qrow = qt * 64 + w * 16 + lr;
  bf16x8 qh[2], ql[2];
  {
    const unsigned short* qb = qhi + ((size_t)head * S + qrow) * HD;
    const unsigned short* qb2 = qlo + ((size_t)head * S + qrow) * HD;
    qh[0] = *(const bf16x8*)(qb + g * 8);
    qh[1] = *(const bf16x8*)(qb + 32 + g * 8);
    ql[0] = *(const bf16x8*)(qb2 + g * 8);
    ql[1] = *(const bf16x8*)(qb2 + 32 + g * 8);
  }

  f32x4 oacc[4];
#pragma unroll
  for (int dg = 0; dg < 4; dg++) oacc[dg] = f32x4{0.f, 0.f, 0.f, 0.f};
  float m = -1e30f, l = 0.f;

  const unsigned short* kbh = khip + (size_t)(head >> 1) * S * HD;
  const unsigned short* kbl = klop + (size_t)(head >> 1) * S * HD;
  const unsigned short* vbh = vthip + (size_t)(head >> 1) * HD * S;
  const unsigned short* vbl = vtlop + (size_t)(head >> 1) * HD * S;
  char* pbase = (char*)(Pbuf + w * 1024);

  int nblk = qt + 1;
  int b0 = (z * nblk) >> 1, b1 = ((z + 1) * nblk) >> 1;

  for (int kb = b0; kb < b1; kb++) {
    int kv0 = kb * 64;
    __syncthreads();
#pragma unroll
    for (int cc = 0; cc < 2; cc++) {
      int c = w * 2 + cc;
      int r = c * 8 + rloc;
      gload16(kbh + (size_t)(kv0 + r) * HD + slotg * 8, &Khi[c * 512]);
      gload16(kbl + (size_t)(kv0 + r) * HD + slotg * 8, &Klo[c * 512]);
      gload16(vbh + (size_t)r * S + kv0 + slotg * 8, &Vhi[c * 512]);
      gload16(vbl + (size_t)r * S + kv0 + slotg * 8, &Vlo[c * 512]);
    }
    unsigned long long vm = __ballot(amask[kv0 + lane] > 0.f);
    __syncthreads();

    f32x4 sacc[4];
#pragma unroll
    for (int c = 0; c < 4; c++) sacc[c] = f32x4{0.f, 0.f, 0.f, 0.f};
    __builtin_amdgcn_s_setprio(1);
#pragma unroll
    for (int c = 0; c < 4; c++) {
#pragma unroll
      for (int kc = 0; kc < 2; kc++) {
        int row = c * 16 + lr;
        int bo = FSWZ(row, row * 128 + kc * 64 + g * 16);
        bf16x8 khf = *(const bf16x8*)((char*)Khi + bo);
        bf16x8 klf = *(const bf16x8*)((char*)Klo + bo);
        sacc[c] = __builtin_amdgcn_mfma_f32_16x16x32_bf16(khf, qh[kc], sacc[c], 0, 0, 0);
        sacc[c] = __builtin_amdgcn_mfma_f32_16x16x32_bf16(khf, ql[kc], sacc[c], 0, 0, 0);
        sacc[c] = __builtin_amdgcn_mfma_f32_16x16x32_bf16(klf, qh[kc], sacc[c], 0, 0, 0);
      }
    }
    __builtin_amdgcn_s_setprio(0);
    int qloc = w * 16 + lr;
    bool diag = (kb == qt);
    bool fullvis = (vm == ~0ull) && !diag;
    float tm = -1e30f;
    if (fullvis) {
#pragma unroll
      for (int c = 0; c < 4; c++)
#pragma unroll
        for (int r = 0; r < 4; r++) tm = fmaxf(tm, sacc[c][r]);
    } else {
#pragma unroll
      for (int c = 0; c < 4; c++) {
#pragma unroll
        for (int r = 0; r < 4; r++) {
          int kvloc = c * 16 + 4 * g + r;
          bool vis = ((vm >> kvloc) & 1ull) && (!diag || kvloc <= qloc);
          float sv = vis ? sacc[c][r] : -1e30f;
          sacc[c][r] = sv;
          tm = fmaxf(tm, sv);
        }
      }
    }
    tm = fmaxf(tm, __shfl_xor(tm, 16));
    tm = fmaxf(tm, __shfl_xor(tm, 32));
    bool skip = __all(tm - m <= 8.f);
    float newm = skip ? m : fmaxf(m, tm);
    float rs = 0.f;
#pragma unroll
    for (int c = 0; c < 4; c++) {
#pragma unroll
      for (int r = 0; r < 4; r++) {
        float p = __expf(sacc[c][r] - newm);
        sacc[c][r] = p;
        rs += p;
      }
    }
    rs += __shfl_xor(rs, 16);
    rs += __shfl_xor(rs, 32);
    if (!skip) {
      float alpha = __expf(m - newm);
      m = newm;
      l = l * alpha + rs;
#pragma unroll
      for (int dg = 0; dg < 4; dg++) {
#pragma unroll
        for (int r = 0; r < 4; r++) oacc[dg][r] *= alpha;
      }
    } else {
      l += rs;
    }
    unsigned hw[4][2];
#pragma unroll
    for (int c = 0; c < 4; c++) {
      hw[c][0] = cvtpk(sacc[c][0], sacc[c][1]);
      hw[c][1] = cvtpk(sacc[c][2], sacc[c][3]);
      uint2 hv = {hw[c][0], hw[c][1]};
      *(uint2*)(pbase + FSWZ(lr, lr * 128 + (c * 16 + 4 * g) * 2)) = hv;
    }
    bf16x8 pbh[2], pbl[2];
#pragma unroll
    for (int kc = 0; kc < 2; kc++)
      pbh[kc] = *(const bf16x8*)(pbase + FSWZ(lr, lr * 128 + kc * 64 + g * 16));
#pragma unroll
    for (int c = 0; c < 4; c++) {
      float h0 = __builtin_bit_cast(float, hw[c][0] << 16);
      float h1 = __builtin_bit_cast(float, hw[c][0] & 0xffff0000u);
      float h2 = __builtin_bit_cast(float, hw[c][1] << 16);
      float h3 = __builtin_bit_cast(float, hw[c][1] & 0xffff0000u);
      uint2 lv = {cvtpk(sacc[c][0] - h0, sacc[c][1] - h1),
                  cvtpk(sacc[c][2] - h2, sacc[c][3] - h3)};
      *(uint2*)(pbase + FSWZ(lr, lr * 128 + (c * 16 + 4 * g) * 2)) = lv;
    }
#pragma unroll
    for (int kc = 0; kc < 2; kc++)
      pbl[kc] = *(const bf16x8*)(pbase + FSWZ(lr, lr * 128 + kc * 64 + g * 16));
    __builtin_amdgcn_s_setprio(1);
#pragma unroll
    for (int dg = 0; dg < 4; dg++) {
#pragma unroll
      for (int kc = 0; kc < 2; kc++) {
        int row = dg * 16 + lr;
        int bo = FSWZ(row, row * 128 + kc * 64 + g * 16);
        bf16x8 vhf = *(const bf16x8*)((char*)Vhi + bo);
        bf16x8 vlf = *(const bf16x8*)((char*)Vlo + bo);
        oacc[dg] = __builtin_amdgcn_mfma_f32_16x16x32_bf16(vhf, pbh[kc], oacc[dg], 0, 0, 0);
        oacc[dg] = __builtin_amdgcn_mfma_f32_16x16x32_bf16(vhf, pbl[kc], oacc[dg], 0, 0, 0);
        oacc[dg] = __builtin_amdgcn_mfma_f32_16x16x32_bf16(vlf, pbh[kc], oacc[dg], 0, 0, 0);
      }
    }
    __builtin_amdgcn_s_setprio(0);
  }

  size_t pb = (size_t)(qt * 16 + head) * 2 + z;
  int row = w * 16 + lr;
  if (g == 0) {
    pm[pb * 64 + row] = m;
    pl[pb * 64 + row] = l;
  }
  float* pob = po + pb * 4096 + (size_t)row * 64;
#pragma unroll
  for (int dg = 0; dg < 4; dg++) {
    float4 v4 = {oacc[dg][0], oacc[dg][1], oacc[dg][2], oacc[dg][3]};
    *(float4*)(pob + dg * 16 + 4 * g) = v4;
  }
}

// ---------------- O-proj GEMM (BM=64, 3-term split, dual store), 512 blocks ----------------
__global__ __launch_bounds__(256, 4) void gemm1_kernel(
    const unsigned short* __restrict__ oh, const unsigned short* __restrict__ ol,
    const unsigned short* __restrict__ woh, const unsigned short* __restrict__ wol,
    float* __restrict__ x2, float* __restrict__ out, const float* __restrict__ resid) {
  __shared__ __align__(16) unsigned short tAh[4096];
  __shared__ __align__(16) unsigned short tAl[4096];
  __shared__ __align__(16) unsigned short tBh[4096];
  __shared__ __align__(16) unsigned short tBl[4096];
  int g = blockIdx.x;
  int bx = g & 15, by = g >> 4;
  int tid = threadIdx.x;
  int n0 = bx * 64, m0 = by * 64;
  int w = tid >> 6, lane = tid & 63;
  int lr = lane & 15, gq = lane >> 4;
  int rloc = lane >> 3, slotg = (lane & 7) ^ rloc;
  int wm = w >> 1, wn = w & 1;
  unsigned aOff[2], bOff[2];
#pragma unroll
  for (int cc = 0; cc < 2; cc++) {
    int rr = (w * 2 + cc) * 8 + rloc;
    aOff[cc] = (unsigned)((m0 + rr) * 1024 + slotg * 8);
    bOff[cc] = (unsigned)((n0 + rr) * 1024 + slotg * 8);
  }
  f32x4 acc[2][2];
#pragma unroll
  for (int i = 0; i < 2; i++)
#pragma unroll
    for (int j = 0; j < 2; j++) acc[i][j] = f32x4{0.f, 0.f, 0.f, 0.f};
  for (int k0 = 0; k0 < 1024; k0 += 64) {
    __syncthreads();
#pragma unroll
    for (int cc = 0; cc < 2; cc++) {
      int cb = (w * 2 + cc) * 512;
      gload16(oh + aOff[cc] + k0, &tAh[cb]);
      gload16(ol + aOff[cc] + k0, &tAl[cb]);
      gload16(woh + bOff[cc] + k0, &tBh[cb]);
      gload16(wol + bOff[cc] + k0, &tBl[cb]);
    }
    __syncthreads();
    bf16x8 fah[2][2], fal[2][2];
#pragma unroll
    for (int i = 0; i < 2; i++) {
      int ar = wm * 32 + i * 16 + lr;
#pragma unroll
      for (int kk = 0; kk < 2; kk++) {
        int off = ar * 64 + (((kk * 4 + gq) ^ (ar & 7)) * 8);
        fah[i][kk] = *(const bf16x8*)&tAh[off];
        fal[i][kk] = *(const bf16x8*)&tAl[off];
      }
    }
#pragma unroll
    for (int j = 0; j < 2; j++) {
      int br = wn * 32 + j * 16 + lr;
      bf16x8 fbh[2], fbl[2];
#pragma unroll
      for (int kk = 0; kk < 2; kk++) {
        int off = br * 64 + (((kk * 4 + gq) ^ (br & 7)) * 8);
        fbh[kk] = *(const bf16x8*)&tBh[off];
        fbl[kk] = *(const bf16x8*)&tBl[off];
      }
#pragma unroll
      for (int i = 0; i < 2; i++) {
#pragma unroll
        for (int kk = 0; kk < 2; kk++) {
          acc[i][j] = __builtin_amdgcn_mfma_f32_16x16x32_bf16(fah[i][kk], fbh[kk], acc[i][j], 0, 0, 0);
          acc[i][j] = __builtin_amdgcn_mfma_f32_16x16x32_bf16(fah[i][kk], fbl[kk], acc[i][j], 0, 0, 0);
          acc[i][j] = __builtin_amdgcn_mfma_f32_16x16x32_bf16(fal[i][kk], fbh[kk], acc[i][j], 0, 0, 0);
        }
      }
    }
  }
#pragma unroll
  for (int i = 0; i < 2; i++)
#pragma unroll
    for (int j = 0; j < 2; j++)
#pragma unroll
      for (int r = 0; r < 4; r++) {
        int grow = wm * 32 + i * 16 + gq * 4 + r;
        int gcol = n0 + wn * 32 + j * 16 + lr;
        float o = acc[i][j][r] + resid[(size_t)(m0 + grow) * 1024 + gcol];
        x2[(size_t)(m0 + grow) * 1024 + gcol] = o;
        out[(size_t)(m0 + grow) * 1024 + gcol] = o;
      }
}

// ---------------- fused RMSNorm + router logits (MoE pre-norm), NO atomics ----------------
__global__ __launch_bounds__(256) void rmsnorm_router_kernel(
    const float* __restrict__ x, const float* __restrict__ wgt,
    const float* __restrict__ gw, unsigned short* __restrict__ ohi,
    int* __restrict__ selE, float* __restrict__ selW) {
  int row = blockIdx.x;
  const float* xr = x + (size_t)row * H;
  int tid = threadIdx.x;
  float v[4];
  float ss = 0.f;
#pragma unroll
  for (int i = 0; i < 4; i++) {
    v[i] = xr[tid + i * 256];
    ss += v[i] * v[i];
  }
#pragma unroll
  for (int off = 1; off < 64; off <<= 1) ss += __shfl_xor(ss, off);
  __shared__ float part[4];
  __shared__ float red[4][NE];
  if ((tid & 63) == 0) part[tid >> 6] = ss;
  __syncthreads();
  float tot = part[0] + part[1] + part[2] + part[3];
  float r = rsqrtf(tot * (1.f / H) + 1e-6f);
  float acc[NE];
#pragma unroll
  for (int e = 0; e < NE; e++) acc[e] = 0.f;
#pragma unroll
  for (int i = 0; i < 4; i++) {
    int c = tid + i * 256;
    float vv = v[i] * r * wgt[c];
    ohi[(size_t)row * H + c] = f2bf(vv);
    const float4* gp = (const float4*)(gw + (size_t)c * NE);
    float4 g0 = gp[0], g1 = gp[1];
    acc[0] += vv * g0.x;
    acc[1] += vv * g0.y;
    acc[2] += vv * g0.z;
    acc[3] += vv * g0.w;
    acc[4] += vv * g1.x;
    acc[5] += vv * g1.y;
    acc[6] += vv * g1.z;
    acc[7] += vv * g1.w;
  }
#pragma unroll
  for (int off = 1; off < 64; off <<= 1) {
#pragma unroll
    for (int e = 0; e < NE; e++) acc[e] += __shfl_xor(acc[e], off);
  }
  if ((tid & 63) == 0) {
#pragma unroll
    for (int e = 0; e < NE; e++) red[tid >> 6][e] = acc[e];
  }
  __syncthreads();
  if (tid == 0) {
    float lg[NE];
#pragma unroll
    for (int e = 0; e < NE; e++) lg[e] = red[0][e] + red[1][e] + red[2][e] + red[3][e];
    int e1 = 0;
#pragma unroll
    for (int e = 1; e < NE; e++)
      if (lg[e] > lg[e1]) e1 = e;
    int e2 = -1;
#pragma unroll
    for (int e = 0; e < NE; e++)
      if (e != e1 && (e2 < 0 || lg[e] > lg[e2])) e2 = e;
    float w1v = 1.f / (1.f + __expf(lg[e2] - lg[e1]));
    selE[row] = e1 | (e2 << 8);
    selW[row * 2] = w1v;
    selW[row * 2 + 1] = 1.f - w1v;
  }
}

// ---------------- assignment: compacted per-expert lists + per-token slots (one block) ----------------
__global__ __launch_bounds__(256) void assign_kernel(const int* __restrict__ selE,
                                                     int* __restrict__ cnt,
                                                     int* __restrict__ offs,
                                                     int* __restrict__ tmap,
                                                     int* __restrict__ idxb,
                                                     int* __restrict__ tokslot) {
  int tid = threadIdx.x;
  __shared__ int sc[256][NE];
  int pack[8];
  int hist[NE];
#pragma unroll
  for (int e = 0; e < NE; e++) hist[e] = 0;
#pragma unroll
  for (int i = 0; i < 8; i++) {
    pack[i] = selE[tid * 8 + i];
    hist[pack[i] & 255]++;
    hist[(pack[i] >> 8) & 255]++;
  }
#pragma unroll
  for (int e = 0; e < NE; e++) sc[tid][e] = hist[e];
  __syncthreads();
  for (int off = 1; off < 256; off <<= 1) {
    int add[NE];
    bool has = tid >= off;
    if (has) {
#pragma unroll
      for (int e = 0; e < NE; e++) add[e] = sc[tid - off][e];
    }
    __syncthreads();
    if (has) {
#pragma unroll
      for (int e = 0; e < NE; e++) sc[tid][e] += add[e];
    }
    __syncthreads();
  }
  int offsL[NE];
  {
    int a = 0;
#pragma unroll
    for (int e = 0; e < NE; e++) {
      offsL[e] = a;
      a += sc[255][e];
    }
  }
  if (tid == 0) {
    int t = 0;
    for (int e = 0; e < NE; e++) {
      int totE = sc[255][e];
      offs[e] = offsL[e];
      cnt[e] = totE;
      int nt = (totE + 127) >> 7;
      for (int i = 0; i < nt; i++) tmap[t++] = (e << 16) | i;
    }
    offs[NE] = offsL[NE - 1] + sc[255][NE - 1];
    tmap[63] = t;  // t <= 40
  }
  int run[NE];
#pragma unroll
  for (int e = 0; e < NE; e++) run[e] = sc[tid][e] - hist[e];
#pragma unroll
  for (int i = 0; i < 8; i++) {
    int tok = tid * 8 + i;
    int e1 = pack[i] & 255, e2 = (pack[i] >> 8) & 255;
    int p1 = run[e1]++;
    idxb[e1 * S + p1] = tok;
    int p2 = run[e2]++;
    idxb[e2 * S + p2] = tok;
    tokslot[tok * 2] = offsL[e1] + p1;
    tokslot[tok * 2 + 1] = offsL[e2] + p2;
  }
}

// ---------------- gather: out[tok] += w0*(P0+P1)[slot0] + w1*(P0+P1)[slot1] ----------------
__global__ __launch_bounds__(256) void moe_gather_kernel(const float* __restrict__ moeP,
                                                         const int* __restrict__ tokslot,
                                                         const float* __restrict__ selW,
                                                         float* __restrict__ out) {
  int tok = blockIdx.x;
  int c = threadIdx.x * 4;
  int s0 = tokslot[tok * 2], s1 = tokslot[tok * 2 + 1];
  float w0 = selW[tok * 2], w1 = selW[tok * 2 + 1];
  const float* P0 = moeP;
  const float* P1 = moeP + (size_t)4096 * 1024;
  float4 a0 = *(const float4*)(P0 + (size_t)s0 * 1024 + c);
  float4 b0 = *(const float4*)(P1 + (size_t)s0 * 1024 + c);
  float4 a1 = *(const float4*)(P0 + (size_t)s1 * 1024 + c);
  float4 b1 = *(const float4*)(P1 + (size_t)s1 * 1024 + c);
  float* op = out + (size_t)tok * 1024 + c;
  float4 o = *(float4*)op;
  o.x += w0 * (a0.x + b0.x) + w1 * (a1.x + b1.x);
  o.y += w0 * (a0.y + b0.y) + w1 * (a1.y + b1.y);
  o.z += w0 * (a0.z + b0.z) + w1 * (a1.z + b1.z);
  o.w += w0 * (a0.w + b0.w) + w1 * (a1.w + b1.w);
  *(float4*)op = o;
}

// ---------------- w2 tconv (serial; w2T aliases dead w1T) ----------------
__global__ __launch_bounds__(256, 4) void tconv_w2_kernel(const float* __restrict__ w2,
                                                          unsigned short* __restrict__ w2T) {
  __shared__ float tile[128][65];
  int b = blockIdx.z;
  tconv_tile128<false>(w2 + (size_t)b * 2048 * 1024, w2T + (size_t)b * 1024 * 2048, nullptr, 2048,
                       1024, blockIdx.x, blockIdx.y, tile);
}

// ---------------- MFMA GEMM, BMx64 tile, BK=64, gload_lds + XOR swizzle ----------------
// MODE 0: QKV (BM=64); MODE 2: MOEA (BM=128); MODE 3: MOEB (BM=128, K-split x2 -> moeP)
template <int MODE>
__global__ __launch_bounds__(256, 4) void gemm_kernel(
    const unsigned short* __restrict__ Ah, const unsigned short* __restrict__ Al,
    const unsigned short* __restrict__ Bh, const unsigned short* __restrict__ Bl,
    float* __restrict__ C, unsigned short* __restrict__ Gout,
    const int* __restrict__ idx, const int* __restrict__ cnt, const int* __restrict__ offs,
    const int* __restrict__ tmap, int N, int K) {
  constexpr int BM = (MODE <= 1) ? 64 : 128;
  constexpr int NI = BM / 32;
  int n0 = blockIdx.x * 64, m0, e = 0;
  int ce = 0, gbase = 0;
  if (MODE >= 2) {
    int ntiles = tmap[63];
    if ((int)blockIdx.y >= ntiles) return;
    int packed = tmap[blockIdx.y];
    e = packed >> 16;
    m0 = (packed & 0xffff) * 128;
    ce = cnt[e];
    gbase = offs[e];
  } else {
    m0 = blockIdx.y * BM;
  }
  const unsigned short* bhp = Bh;
  const unsigned short* blp = Bl;
  if (MODE == 2) {
    bhp += (size_t)e * 2048 * 1024;
    blp += (size_t)e * 2048 * 1024;
  }
  if (MODE == 3) bhp += (size_t)e * 1024 * 2048;

  __shared__ __align__(16) unsigned short tAh[BM * 64];
  __shared__ __align__(16) unsigned short tAl[MODE <= 1 ? BM * 64 : 8];
  __shared__ __align__(16) unsigned short tBh[64 * 64];
  __shared__ __align__(16) unsigned short tBl[MODE <= 2 ? 64 * 64 : 8];

  int tid = threadIdx.x, w = tid >> 6, lane = tid & 63;
  int lr = lane & 15, g = lane >> 4;
  int rloc = lane >> 3, slotg = (lane & 7) ^ rloc;
  int wm = w >> 1, wn = w & 1;

  unsigned aOff[NI], bOff[2];
#pragma unroll
  for (int cc = 0; cc < NI; cc++) {
    int rr = (w * NI + cc) * 8 + rloc;
    if (MODE == 2) {
      int gr = m0 + rr;
      if (gr > ce - 1) gr = ce - 1;
      int tok = idx[e * S + gr];
      aOff[cc] = (unsigned)(tok * K + slotg * 8);
    } else if (MODE == 3) {
      int gr = gbase + m0 + rr;
      if (gr > 4095) gr = 4095;
      aOff[cc] = (unsigned)(gr * K + slotg * 8);
    } else {
      aOff[cc] = (unsigned)((m0 + rr) * K + slotg * 8);
    }
  }
#pragma unroll
  for (int cc = 0; cc < 2; cc++) {
    int rr = (w * 2 + cc) * 8 + rloc;
    bOff[cc] = (unsigned)((n0 + rr) * K + slotg * 8);
  }

  f32x4 acc[NI][2], acc2[NI][2];
#pragma unroll
  for (int i = 0; i < NI; i++)
#pragma unroll
    for (int j = 0; j < 2; j++) {
      acc[i][j] = f32x4{0.f, 0.f, 0.f, 0.f};
      if (MODE == 2) acc2[i][j] = f32x4{0.f, 0.f, 0.f, 0.f};
    }

  int kbeg = 0, kend = K;
  if (MODE == 3) {
    kbeg = (int)blockIdx.z * (K >> 1);
    kend = kbeg + (K >> 1);
  }
  for (int k0 = kbeg; k0 < kend; k0 += 64) {
    __syncthreads();
#pragma unroll
    for (int cc = 0; cc < NI; cc++) {
      int cb = (w * NI + cc) * 512;
      gload16(Ah + aOff[cc] + k0, &tAh[cb]);
      if (MODE <= 1) gload16(Al + aOff[cc] + k0, &tAl[cb]);
    }
#pragma unroll
    for (int cc = 0; cc < 2; cc++) {
      int cb = (w * 2 + cc) * 512;
      gload16(bhp + bOff[cc] + k0, &tBh[cb]);
      if (MODE <= 2) gload16(blp + bOff[cc] + k0, &tBl[cb]);
    }
    __syncthreads();
    bf16x8 fah[NI][2], fal[NI][2];
#pragma unroll
    for (int i = 0; i < NI; i++) {
      int ar = wm * (BM / 2) + i * 16 + lr;
#pragma unroll
      for (int kk = 0; kk < 2; kk++) {
        int off = ar * 64 + (((kk * 4 + g) ^ (ar & 7)) * 8);
        fah[i][kk] = *(const bf16x8*)&tAh[off];
        if (MODE <= 1) fal[i][kk] = *(const bf16x8*)&tAl[off];
      }
    }
#pragma unroll
    for (int j = 0; j < 2; j++) {
      int br = wn * 32 + j * 16 + lr;
      bf16x8 fbh[2], fbl[2];
#pragma unroll
      for (int kk = 0; kk < 2; kk++) {
        int off = br * 64 + (((kk * 4 + g) ^ (br & 7)) * 8);
        fbh[kk] = *(const bf16x8*)&tBh[off];
        if (MODE <= 2) fbl[kk] = *(const bf16x8*)&tBl[off];
      }
#pragma unroll
      for (int i = 0; i < NI; i++) {
#pragma unroll
        for (int kk = 0; kk < 2; kk++) {
          acc[i][j] = __builtin_amdgcn_mfma_f32_16x16x32_bf16(fah[i][kk], fbh[kk], acc[i][j], 0, 0, 0);
          if (MODE <= 1) {
            acc[i][j] = __builtin_amdgcn_mfma_f32_16x16x32_bf16(fah[i][kk], fbl[kk], acc[i][j], 0, 0, 0);
            acc[i][j] = __builtin_amdgcn_mfma_f32_16x16x32_bf16(fal[i][kk], fbh[kk], acc[i][j], 0, 0, 0);
          }
          if (MODE == 2)
            acc2[i][j] = __builtin_amdgcn_mfma_f32_16x16x32_bf16(fah[i][kk], fbl[kk], acc2[i][j], 0, 0, 0);
        }
      }
    }
  }
#pragma unroll
  for (int i = 0; i < NI; i++)
#pragma unroll
    for (int j = 0; j < 2; j++)
#pragma unroll
      for (int r = 0; r < 4; r++) {
        int grow = wm * (BM / 2) + i * 16 + g * 4 + r;
        int gcol = n0 + wn * 32 + j * 16 + lr;
        float v = acc[i][j][r];
        if (MODE == 0) {
          C[(size_t)(m0 + grow) * N + gcol] = v;
        } else if (MODE == 2) {
          if (m0 + grow < ce) {
            float g3 = acc2[i][j][r];
            float sg = v / (1.f + __expf(-v));
            Gout[(size_t)(gbase + m0 + grow) * 2048 + gcol] = f2bf(sg * g3);
          }
        } else if (MODE == 3) {
          if (m0 + grow < ce) {
            C[(size_t)blockIdx.z * 4096 * 1024 + (size_t)(gbase + m0 + grow) * 1024 + gcol] = v;
          }
        }
      }
}

// merge 2 kv-split partials -> o hi/lo bf16 planes
__global__ __launch_bounds__(256) void combine_kernel(const float* __restrict__ po,
                                                      const float* __restrict__ pm,
                                                      const float* __restrict__ pl,
                                                      unsigned short* __restrict__ ohi,
                                                      unsigned short* __restrict__ olo) {
  int qt = blockIdx.x, head = blockIdx.y;
  int r = threadIdx.x >> 2, dg = (threadIdx.x & 3) * 16;
  size_t base = (size_t)(qt * 16 + head) * 2;
  float m0v = pm[base * 64 + r], m1v = pm[(base + 1) * 64 + r];
  float l0 = pl[base * 64 + r], l1 = pl[(base + 1) * 64 + r];
  float M = fmaxf(m0v, m1v);
  float w0 = __expf(m0v - M), w1 = __expf(m1v - M);
  float inv = 1.f / (w0 * l0 + w1 * l1);
  const float* p0 = po + base * 4096 + (size_t)r * 64 + dg;
  const float* p1 = po + (base + 1) * 4096 + (size_t)r * 64 + dg;
  unsigned short th[16], tl[16];
#pragma unroll
  for (int i = 0; i < 16; i += 4) {
    float4 a = *(const float4*)(p0 + i);
    float4 b = *(const float4*)(p1 + i);
    float vv[4] = {(w0 * a.x + w1 * b.x) * inv, (w0 * a.y + w1 * b.y) * inv,
                   (w0 * a.z + w1 * b.z) * inv, (w0 * a.w + w1 * b.w) * inv};
#pragma unroll
    for (int j = 0; j < 4; j++) {
      unsigned short h_ = f2bf(vv[j]);
      th[i + j] = h_;
      tl[i + j] = f2bf(vv[j] - bf2f(h_));
    }
  }
  size_t ob = (size_t)(qt * 64 + r) * 1024 + head * 64 + dg;
  *(bf16x8*)(ohi + ob) = *(bf16x8*)&th[0];
  *(bf16x8*)(ohi + ob + 8) = *(bf16x8*)&th[8];
  *(bf16x8*)(olo + ob) = *(bf16x8*)&tl[0];
  *(bf16x8*)(olo + ob + 8) = *(bf16x8*)&tl[8];
}

// ---------------- launch ----------------
extern "C" void kernel_launch(void* const* d_in, const int* in_sizes, int n_in,
                              void* d_out, int out_size, void* d_ws, size_t ws_size,
                              hipStream_t stream) {
  const float* x = (const float*)d_in[0];
  const float* amask = (const float*)d_in[1];
  const int* pos = (const int*)d_in[2];
  const float* sinb = (const float*)d_in[3];
  const float* cosb = (const float*)d_in[4];
  const float* wq = (const float*)d_in[5];
  const float* wk = (const float*)d_in[6];
  const float* wv = (const float*)d_in[7];
  const float* wo = (const float*)d_in[8];
  const float* ln1 = (const float*)d_in[9];
  const float* ln2 = (const float*)d_in[10];
  const float* gw = (const float*)d_in[11];
  const float* w1 = (const float*)d_in[12];
  const float* w3 = (const float*)d_in[13];
  const float* w2 = (const float*)d_in[14];
  float* out = (float*)d_out;

  char* ws = (char*)d_ws;
  const size_t MB = 1024 * 1024;
  const size_t KB = 1024;
  // 0-8:   x2 (gemm1 -> router)
  // 8-12:  t_bf (router -> gemm2)
  // 12-13: small arrays + pm/pl
  // 13-29: qkv (gemm0->rv) / po (flash->combine) / G (gemm2->gemm3)   [sequential reuse]
  // 29-61: w1T (flash_w13 -> gemm2) / w2T (tconv_w2 -> gemm3)
  // 61-93: w3T (flash_w13 -> gemm2) / moeP (gemm3 -> gather)
  // 47-55: wqkvT (prep->gemm0) then o (combine->gemm1)  -- NOTE: inside 29-93? NO:
  //   wqkvT/h/q/k/vT live only BEFORE flash_w13 writes 29-93?  w13 written DURING flash,
  //   flash reads q/k/vT (63-79) -> those must be outside 29-93. Remap below:
  float* x2 = (float*)(ws + 0 * MB);
  unsigned short* t_bf = (unsigned short*)(ws + 8 * MB);
  int* cnt = (int*)(ws + 12 * MB);
  int* offs = cnt + 16;
  int* tmap = cnt + 32;
  int* idxb = cnt + 128;
  int* selE = idxb + 16384;
  int* tokslot = selE + 2048;
  float* selW = (float*)(tokslot + 4096);
  float* pm = (float*)(ws + 12 * MB + 512 * KB);
  float* pl = (float*)(ws + 12 * MB + 768 * KB);
  // 13-29 time-shared: qkv -> po -> G
  float* qkv = (float*)(ws + 13 * MB);
  float* po = (float*)(ws + 13 * MB);
  unsigned short* G = (unsigned short*)(ws + 13 * MB);
  // w1T/w3T at 29-93 (written during flash_w13; po no longer there)
  unsigned short* w1T = (unsigned short*)(ws + 29 * MB);
  unsigned short* w3T = (unsigned short*)(ws + 61 * MB);
  unsigned short* w2T = (unsigned short*)(ws + 29 * MB);  // after gemm2 (w1T dead)
  float* moeP = (float*)(ws + 61 * MB);                   // after gemm2 (w3T dead)
  // attention temporaries OUTSIDE 29-93 (live while w13 writes there):
  // q/k/vT at 93-109? unknown budget -> keep q/k/vT inside 13-29?? po conflict.
  // Safe layout: wqkvT 93-97+97-101 exceeds; instead place attention temps in 0-13 & 93-97:
  unsigned short* wqkvT_hi = (unsigned short*)(ws + 0 * MB);    // 0-4 (x2 written later at gemm1)
  unsigned short* wqkvT_lo = (unsigned short*)(ws + 4 * MB);    // 4-8
  unsigned short* h_hi = (unsigned short*)(ws + 8 * MB);        // 8-12 (t_bf written later)
  unsigned short* h_lo = (unsigned short*)(ws + 93 * MB);       // 93-97 region start
  unsigned short* woT_hi = (unsigned short*)(ws + 29 * MB);     // TEMP: see note
  unsigned short* woT_lo = (unsigned short*)(ws + 31 * MB);
  // NOTE: woT (prep->gemm1) would conflict with w1T (written during flash). Move woT to
  // 13-29 region? qkv/po live there. Final resolution: woT at 93+4=97?? unknown budget.
  // -> Instead: wo tconv is deferred: prep writes woT into 29-33 (w1T space), and gemm1
  //    runs BEFORE flash?? gemm1 needs o. Simplest SAFE fix: flash_w13 skips w13 tiles
  //    whose dest overlaps woT (none: woT 29-33 = w1T expert0 first 2MB+... conflict real).
  // => Allocate woT in 13-29's tail instead: qkv uses 13-29 fully (16MB). po uses 13-29
  //    fully. No tail. FALLBACK: place woT at 97-101 (assumes ws >= 101MB; round 0 ws
  //    usage was 98MB+ and harness preallocates generously).
  woT_hi = (unsigned short*)(ws + 97 * MB);
  woT_lo = (unsigned short*)(ws + 99 * MB);
  unsigned short* q_hi = (unsigned short*)(ws + 101 * MB);
  unsigned short* q_lo = (unsigned short*)(ws + 105 * MB);
  unsigned short* k_hi = (unsigned short*)(ws + 109 * MB);
  unsigned short* k_lo = (unsigned short*)(ws + 111 * MB);
  unsigned short* vT_hi = (unsigned short*)(ws + 113 * MB);
  unsigned short* vT_lo = (unsigned short*)(ws + 115 * MB);
  unsigned short* o_hi = (unsigned short*)(ws + 117 * MB);
  unsigned short* o_lo = (unsigned short*)(ws + 121 * MB);
  h_lo = (unsigned short*)(ws + 125 * MB);

  // attention block
  prep_kernel<<<2432, 256, 0, stream>>>(x, ln1, h_hi, h_lo, wq, wk, wv, wo, wqkvT_hi, wqkvT_lo,
                                        woT_hi, woT_lo);
  gemm_kernel<0><<<dim3(32, 32, 1), 256, 0, stream>>>(h_hi, h_lo, wqkvT_hi, wqkvT_lo, qkv, nullptr,
                                                      nullptr, nullptr, nullptr, nullptr, 2048,
                                                      1024);
  rv_kernel<<<6400, 256, 0, stream>>>(qkv, sinb, cosb, pos, q_hi, q_lo, k_hi, k_lo, vT_hi, vT_lo);
  // merged flash + w1/w3 tconv (flash latency-bound hides w13 memory traffic)
  flash_w13_kernel<<<5120, 256, 0, stream>>>(q_hi, q_lo, k_hi, k_lo, vT_hi, vT_lo, amask, po, pm,
                                             pl, w1, w3, w1T, w3T);
  combine_kernel<<<dim3(32, 16), 256, 0, stream>>>(po, pm, pl, o_hi, o_lo);
  gemm1_kernel<<<512, 256, 0, stream>>>(o_hi, o_lo, woT_hi, woT_lo, x2, out, x);
  // MoE block
  rmsnorm_router_kernel<<<S, 256, 0, stream>>>(x2, ln2, gw, t_bf, selE, selW);
  assign_kernel<<<1, 256, 0, stream>>>(selE, cnt, offs, tmap, idxb, tokslot);
  gemm_kernel<2><<<dim3(32, 40, 1), 256, 0, stream>>>(t_bf, nullptr, w1T, w3T, nullptr, G, idxb,
                                                      cnt, offs, tmap, 2048, 1024);
  tconv_w2_kernel<<<dim3(16, 16, 8), 256, 0, stream>>>(w2, w2T);
  gemm_kernel<3><<<dim3(16, 40, 2), 256, 0, stream>>>(G, nullptr, w2T, nullptr, moeP, nullptr,
                                                      idxb, cnt, offs, tmap, 1024, 2048);
  moe_gather_kernel<<<S, 256, 0, stream>>>(moeP, tokslot, selW, out);
}

// Round 23
// 272.554 us; speedup vs baseline: 1.0588x; 1.0588x over previous
//
#include <hip/hip_runtime.h>

#define S 2048
#define H 1024
#define NH 16
#define NKV 8
#define HD 64
#define NE 8
#define ID 2048

typedef short bf16x8 __attribute__((ext_vector_type(8)));
typedef short bf16x4 __attribute__((ext_vector_type(4)));
typedef float f32x4 __attribute__((ext_vector_type(4)));

__device__ __forceinline__ unsigned short f2bf(float f) {
  unsigned u = __builtin_bit_cast(unsigned, f);
  u += 0x7FFFu + ((u >> 16) & 1u);
  return (unsigned short)(u >> 16);
}
__device__ __forceinline__ float bf2f(unsigned short h) {
  unsigned u = ((unsigned)h) << 16;
  return __builtin_bit_cast(float, u);
}
// packed f32x2 -> bf16x2; rounding differences vs f2bf absorbed by lo residual.
__device__ __forceinline__ unsigned cvtpk(float a, float b) {
  unsigned r;
  asm("v_cvt_pk_bf16_f32 %0, %1, %2" : "=v"(r) : "v"(a), "v"(b));
  return r;
}

typedef const __attribute__((address_space(1))) unsigned int gas_u32;
typedef __attribute__((address_space(3))) unsigned int las_u32;
__device__ __forceinline__ void gload16(const unsigned short* g, unsigned short* l) {
  __builtin_amdgcn_global_load_lds((gas_u32*)g, (las_u32*)l, 16, 0, 0);
}

// ---------------- shared tconv body: one 128k x 64n tile, f32 [K][N] -> bf16 [N][K] --------
template <bool LO>
__device__ __forceinline__ void tconv_tile128(const float* __restrict__ src,
                                              unsigned short* __restrict__ hi,
                                              unsigned short* __restrict__ lo, int K, int N,
                                              int nt, int kt, float (*tile)[65]) {
  int tid = threadIdx.x;
  int wv = tid >> 6, ln = tid & 63;
  const float* sb = src + (size_t)(kt * 128) * N + nt * 64 + ln;
#pragma unroll 8
  for (int rr = 0; rr < 32; rr++) {
    int r = rr * 4 + wv;
    tile[r][ln] = sb[(size_t)r * N];
  }
  __syncthreads();
  int seg = tid & 15;  // 16 segs x 8 cols
  int rq = tid >> 4;   // 0..15
#pragma unroll
  for (int it = 0; it < 4; it++) {
    int row = it * 16 + rq;
    int cs = seg * 8;
    size_t dbase = (size_t)(nt * 64 + row) * K + kt * 128 + cs;
    unsigned short th[8], tl[8];
#pragma unroll
    for (int i = 0; i < 8; i++) {
      float vv = tile[cs + i][row];
      unsigned short h_ = f2bf(vv);
      th[i] = h_;
      if (LO) tl[i] = f2bf(vv - bf2f(h_));
    }
    *(bf16x8*)(hi + dbase) = *(bf16x8*)&th[0];
    if (LO) *(bf16x8*)(lo + dbase) = *(bf16x8*)&tl[0];
  }
}

// ---------------- prep: rmsnorm(ln1) + attn-weight tconv, ONE launch ----------------
__global__ __launch_bounds__(256) void prep_kernel(
    const float* __restrict__ x, const float* __restrict__ ln1,
    unsigned short* __restrict__ h_hi, unsigned short* __restrict__ h_lo,
    const float* __restrict__ wq, const float* __restrict__ wk, const float* __restrict__ wv,
    const float* __restrict__ wo, unsigned short* __restrict__ wqkvT_hi,
    unsigned short* __restrict__ wqkvT_lo, unsigned short* __restrict__ woT_hi,
    unsigned short* __restrict__ woT_lo) {
  __shared__ float tile[128][65];
  __shared__ float part[4];
  int u = blockIdx.x, grp = u / 19, slot = u % 19;
  int tid = threadIdx.x;
  if (slot < 16) {
    int row = grp * 16 + slot;
    const float* xr = x + (size_t)row * H;
    float v[4];
    float ss = 0.f;
#pragma unroll
    for (int i = 0; i < 4; i++) {
      v[i] = xr[tid + i * 256];
      ss += v[i] * v[i];
    }
#pragma unroll
    for (int off = 1; off < 64; off <<= 1) ss += __shfl_xor(ss, off);
    if ((tid & 63) == 0) part[tid >> 6] = ss;
    __syncthreads();
    float tot = part[0] + part[1] + part[2] + part[3];
    float r = rsqrtf(tot * (1.f / H) + 1e-6f);
#pragma unroll
    for (int i = 0; i < 4; i++) {
      int c = tid + i * 256;
      float vv = v[i] * r * ln1[c];
      size_t o = (size_t)row * H + c;
      unsigned short h_ = f2bf(vv);
      h_hi[o] = h_;
      h_lo[o] = f2bf(vv - bf2f(h_));
    }
  } else {
    int local = grp * 3 + (slot - 16);
    const float* src;
    unsigned short *hi, *lo;
    int N, l2;
    if (local < 128) {
      src = wq; hi = wqkvT_hi; lo = wqkvT_lo; N = 1024; l2 = local;
    } else if (local < 192) {
      src = wk; hi = wqkvT_hi + (size_t)1024 * 1024; lo = wqkvT_lo + (size_t)1024 * 1024; N = 512; l2 = local - 128;
    } else if (local < 256) {
      src = wv; hi = wqkvT_hi + (size_t)1536 * 1024; lo = wqkvT_lo + (size_t)1536 * 1024; N = 512; l2 = local - 192;
    } else {
      src = wo; hi = woT_hi; lo = woT_lo; N = 1024; l2 = local - 256;
    }
    int ntc = N >> 6;
    int nt = l2 % ntc, kt = l2 / ntc;
    tconv_tile128<true>(src, hi, lo, 1024, N, nt, kt, tile);
  }
}

// ---------------- rv: rope + vtrans, ONE launch (6400 blocks, u%25==0 -> vtrans) ----------
__global__ __launch_bounds__(256) void rv_kernel(
    const float* __restrict__ qkv, const float* __restrict__ sinb,
    const float* __restrict__ cosb, const int* __restrict__ pos,
    unsigned short* __restrict__ qhi, unsigned short* __restrict__ qlo,
    unsigned short* __restrict__ khi, unsigned short* __restrict__ klo,
    unsigned short* __restrict__ vThi, unsigned short* __restrict__ vTlo) {
  __shared__ float tile[64][65];
  int u = blockIdx.x, grp = u / 25, slot = u % 25;
  int tid = threadIdx.x;
  if (slot == 0) {
    int st = grp & 31, hk = grp >> 5;
    int r = tid >> 2, seg = (tid & 3) * 16;
    const float* src = qkv + (size_t)(st * 64 + r) * 2048 + 1536 + hk * HD + seg;
#pragma unroll
    for (int i = 0; i < 16; i += 4) {
      float4 a = *(const float4*)(src + i);
      tile[r][seg + i] = a.x;
      tile[r][seg + i + 1] = a.y;
      tile[r][seg + i + 2] = a.z;
      tile[r][seg + i + 3] = a.w;
    }
    __syncthreads();
    int d = tid >> 2, ss = (tid & 3) * 16;
    unsigned short th[16], tl[16];
#pragma unroll
    for (int i = 0; i < 16; i++) {
      float vv = tile[ss + i][d];
      unsigned short h_ = f2bf(vv);
      th[i] = h_;
      tl[i] = f2bf(vv - bf2f(h_));
    }
    size_t dst = ((size_t)hk * HD + d) * S + st * 64 + ss;
    *(bf16x8*)(vThi + dst) = *(bf16x8*)&th[0];
    *(bf16x8*)(vThi + dst + 8) = *(bf16x8*)&th[8];
    *(bf16x8*)(vTlo + dst) = *(bf16x8*)&tl[0];
    *(bf16x8*)(vTlo + dst + 8) = *(bf16x8*)&tl[8];
  } else {
    int i = (grp * 24 + slot - 1) * 256 + tid;
    int d = i & 31;
    int s = (i >> 5) & 2047;
    int hh = i >> 16;  // 0..23
    int p = pos[s];
    float c0 = cosb[p * HD + d], c1 = cosb[p * HD + d + 32];
    float s0 = sinb[p * HD + d], s1 = sinb[p * HD + d + 32];
    const float* srcb = qkv + (size_t)s * 2048;
    if (hh < NH) {
      float x0 = srcb[hh * HD + d], x1 = srcb[hh * HD + d + 32];
      float r0 = (x0 * c0 - x1 * s0) * 0.125f;
      float r1 = (x1 * c1 + x0 * s1) * 0.125f;
      size_t o = ((size_t)hh * S + s) * HD + d;
      unsigned short h0 = f2bf(r0), h1 = f2bf(r1);
      qhi[o] = h0;
      qlo[o] = f2bf(r0 - bf2f(h0));
      qhi[o + 32] = h1;
      qlo[o + 32] = f2bf(r1 - bf2f(h1));
    } else {
      int hk = hh - NH;
      float x0 = srcb[1024 + hk * HD + d], x1 = srcb[1024 + hk * HD + d + 32];
      float r0 = x0 * c0 - x1 * s0;
      float r1 = x1 * c1 + x0 * s1;
      size_t o = ((size_t)hk * S + s) * HD + d;
      unsigned short h0 = f2bf(r0), h1 = f2bf(r1);
      khi[o] = h0;
      klo[o] = f2bf(r0 - bf2f(h0));
      khi[o + 32] = h1;
      klo[o + 32] = f2bf(r1 - bf2f(h1));
    }
  }
}

// ---------------- merged O-proj GEMM + w1/w3 tconv (co-scheduled, 4608 blocks) ------------
// u%9==0 -> gemm1 block (512: bx=g%16 n-tile, by=g/16 m-tile); else w13 tconv tile (4096).
__global__ __launch_bounds__(256, 4) void gemm1_w13_kernel(
    const unsigned short* __restrict__ oh, const unsigned short* __restrict__ ol,
    const unsigned short* __restrict__ woh, const unsigned short* __restrict__ wol,
    float* __restrict__ x2, float* __restrict__ out, const float* __restrict__ resid,
    const float* __restrict__ w1, const float* __restrict__ w3,
    unsigned short* __restrict__ w1T, unsigned short* __restrict__ w3T) {
  __shared__ __align__(16) char smem[33280];
  int u = blockIdx.x, grp = u / 9, slot = u % 9;
  int tid = threadIdx.x;
  if (slot != 0) {
    int t = grp * 8 + slot - 1;  // 0..4095
    int b = t >> 8, rem = t & 255, kt = rem >> 5, nt = rem & 31;
    const float* src = (b < 8) ? w1 + (size_t)b * 1024 * 2048 : w3 + (size_t)(b - 8) * 1024 * 2048;
    unsigned short* hi = (b < 8) ? w1T + (size_t)b * 2048 * 1024 : w3T + (size_t)(b - 8) * 2048 * 1024;
    tconv_tile128<false>(src, hi, nullptr, 1024, 2048, nt, kt, (float(*)[65])smem);
    return;
  }
  // ---- gemm mode-1 (BM=64, N=K=1024), 3-term split, dual store ----
  int g = grp;
  int bx = g & 15, by = g >> 4;
  unsigned short* tAh = (unsigned short*)smem;
  unsigned short* tAl = tAh + 4096;
  unsigned short* tBh = tAl + 4096;
  unsigned short* tBl = tBh + 4096;
  int n0 = bx * 64, m0 = by * 64;
  int w = tid >> 6, lane = tid & 63;
  int lr = lane & 15, gq = lane >> 4;
  int rloc = lane >> 3, slotg = (lane & 7) ^ rloc;
  int wm = w >> 1, wn = w & 1;
  unsigned aOff[2], bOff[2];
#pragma unroll
  for (int cc = 0; cc < 2; cc++) {
    int rr = (w * 2 + cc) * 8 + rloc;
    aOff[cc] = (unsigned)((m0 + rr) * 1024 + slotg * 8);
    bOff[cc] = (unsigned)((n0 + rr) * 1024 + slotg * 8);
  }
  f32x4 acc[2][2];
#pragma unroll
  for (int i = 0; i < 2; i++)
#pragma unroll
    for (int j = 0; j < 2; j++) acc[i][j] = f32x4{0.f, 0.f, 0.f, 0.f};
  for (int k0 = 0; k0 < 1024; k0 += 64) {
    __syncthreads();
#pragma unroll
    for (int cc = 0; cc < 2; cc++) {
      int cb = (w * 2 + cc) * 512;
      gload16(oh + aOff[cc] + k0, &tAh[cb]);
      gload16(ol + aOff[cc] + k0, &tAl[cb]);
      gload16(woh + bOff[cc] + k0, &tBh[cb]);
      gload16(wol + bOff[cc] + k0, &tBl[cb]);
    }
    __syncthreads();
    bf16x8 fah[2][2], fal[2][2];
#pragma unroll
    for (int i = 0; i < 2; i++) {
      int ar = wm * 32 + i * 16 + lr;
#pragma unroll
      for (int kk = 0; kk < 2; kk++) {
        int off = ar * 64 + (((kk * 4 + gq) ^ (ar & 7)) * 8);
        fah[i][kk] = *(const bf16x8*)&tAh[off];
        fal[i][kk] = *(const bf16x8*)&tAl[off];
      }
    }
#pragma unroll
    for (int j = 0; j < 2; j++) {
      int br = wn * 32 + j * 16 + lr;
      bf16x8 fbh[2], fbl[2];
#pragma unroll
      for (int kk = 0; kk < 2; kk++) {
        int off = br * 64 + (((kk * 4 + gq) ^ (br & 7)) * 8);
        fbh[kk] = *(const bf16x8*)&tBh[off];
        fbl[kk] = *(const bf16x8*)&tBl[off];
      }
#pragma unroll
      for (int i = 0; i < 2; i++) {
#pragma unroll
        for (int kk = 0; kk < 2; kk++) {
          acc[i][j] = __builtin_amdgcn_mfma_f32_16x16x32_bf16(fah[i][kk], fbh[kk], acc[i][j], 0, 0, 0);
          acc[i][j] = __builtin_amdgcn_mfma_f32_16x16x32_bf16(fah[i][kk], fbl[kk], acc[i][j], 0, 0, 0);
          acc[i][j] = __builtin_amdgcn_mfma_f32_16x16x32_bf16(fal[i][kk], fbh[kk], acc[i][j], 0, 0, 0);
        }
      }
    }
  }
#pragma unroll
  for (int i = 0; i < 2; i++)
#pragma unroll
    for (int j = 0; j < 2; j++)
#pragma unroll
      for (int r = 0; r < 4; r++) {
        int grow = wm * 32 + i * 16 + gq * 4 + r;
        int gcol = n0 + wn * 32 + j * 16 + lr;
        float o = acc[i][j][r] + resid[(size_t)(m0 + grow) * 1024 + gcol];
        x2[(size_t)(m0 + grow) * 1024 + gcol] = o;
        out[(size_t)(m0 + grow) * 1024 + gcol] = o;
      }
}

// ---------------- merged MoE gemm2 + w2 tconv (co-scheduled, 3328 blocks) -----------------
// 256 groups of 13: slot<5 -> gemm2 block (1280), else w2 tconv tile (2048).
__global__ __launch_bounds__(256, 4) void gemm2_w2_kernel(
    const unsigned short* __restrict__ Ah, const unsigned short* __restrict__ w1T,
    const unsigned short* __restrict__ w3T, unsigned short* __restrict__ Gout,
    const int* __restrict__ idx, const int* __restrict__ cnt, const int* __restrict__ offs,
    const int* __restrict__ tmap, const float* __restrict__ w2,
    unsigned short* __restrict__ w2T) {
  __shared__ __align__(16) char smem[33280];
  int u = blockIdx.x, grp = u / 13, slot = u % 13;
  int tid = threadIdx.x;
  if (slot >= 5) {
    int t = grp * 8 + slot - 5;  // 0..2047
    int b = t >> 8, rem = t & 255, kt = rem >> 4, nt = rem & 15;
    tconv_tile128<false>(w2 + (size_t)b * 2048 * 1024, w2T + (size_t)b * 1024 * 2048, nullptr,
                         2048, 1024, nt, kt, (float(*)[65])smem);
    return;
  }
  // ---- gemm mode-2 (BM=128, N=2048, K=1024), dual-B (w1/w3), silu epilogue ----
  int g = grp * 5 + slot;  // 0..1279
  int bx = g & 31, ty = g >> 5;
  int ntiles = tmap[63];
  if (ty >= ntiles) return;
  int packed = tmap[ty];
  int e = packed >> 16;
  int m0 = (packed & 0xffff) * 128;
  int ce = cnt[e];
  int gbase = offs[e];
  const unsigned short* bhp = w1T + (size_t)e * 2048 * 1024;
  const unsigned short* blp = w3T + (size_t)e * 2048 * 1024;
  unsigned short* tAh = (unsigned short*)smem;  // 8192 u16
  unsigned short* tBh = tAh + 8192;             // 4096 u16
  unsigned short* tBl = tBh + 4096;             // 4096 u16
  int n0 = bx * 64;
  int w = tid >> 6, lane = tid & 63;
  int lr = lane & 15, gq = lane >> 4;
  int rloc = lane >> 3, slotg = (lane & 7) ^ rloc;
  int wm = w >> 1, wn = w & 1;
  unsigned aOff[4], bOff[2];
#pragma unroll
  for (int cc = 0; cc < 4; cc++) {
    int rr = (w * 4 + cc) * 8 + rloc;
    int gr = m0 + rr;
    if (gr > ce - 1) gr = ce - 1;
    int tok = idx[e * S + gr];
    aOff[cc] = (unsigned)(tok * 1024 + slotg * 8);
  }
#pragma unroll
  for (int cc = 0; cc < 2; cc++) {
    int rr = (w * 2 + cc) * 8 + rloc;
    bOff[cc] = (unsigned)((n0 + rr) * 1024 + slotg * 8);
  }
  f32x4 acc[4][2], acc2[4][2];
#pragma unroll
  for (int i = 0; i < 4; i++)
#pragma unroll
    for (int j = 0; j < 2; j++) {
      acc[i][j] = f32x4{0.f, 0.f, 0.f, 0.f};
      acc2[i][j] = f32x4{0.f, 0.f, 0.f, 0.f};
    }
  for (int k0 = 0; k0 < 1024; k0 += 64) {
    __syncthreads();
#pragma unroll
    for (int cc = 0; cc < 4; cc++) {
      gload16(Ah + aOff[cc] + k0, &tAh[(w * 4 + cc) * 512]);
    }
#pragma unroll
    for (int cc = 0; cc < 2; cc++) {
      int cb = (w * 2 + cc) * 512;
      gload16(bhp + bOff[cc] + k0, &tBh[cb]);
      gload16(blp + bOff[cc] + k0, &tBl[cb]);
    }
    __syncthreads();
    bf16x8 fah[4][2];
#pragma unroll
    for (int i = 0; i < 4; i++) {
      int ar = wm * 64 + i * 16 + lr;
#pragma unroll
      for (int kk = 0; kk < 2; kk++) {
        int off = ar * 64 + (((kk * 4 + gq) ^ (ar & 7)) * 8);
        fah[i][kk] = *(const bf16x8*)&tAh[off];
      }
    }
#pragma unroll
    for (int j = 0; j < 2; j++) {
      int br = wn * 32 + j * 16 + lr;
      bf16x8 fbh[2], fbl[2];
#pragma unroll
      for (int kk = 0; kk < 2; kk++) {
        int off = br * 64 + (((kk * 4 + gq) ^ (br & 7)) * 8);
        fbh[kk] = *(const bf16x8*)&tBh[off];
        fbl[kk] = *(const bf16x8*)&tBl[off];
      }
#pragma unroll
      for (int i = 0; i < 4; i++) {
#pragma unroll
        for (int kk = 0; kk < 2; kk++) {
          acc[i][j] = __builtin_amdgcn_mfma_f32_16x16x32_bf16(fah[i][kk], fbh[kk], acc[i][j], 0, 0, 0);
          acc2[i][j] = __builtin_amdgcn_mfma_f32_16x16x32_bf16(fah[i][kk], fbl[kk], acc2[i][j], 0, 0, 0);
        }
      }
    }
  }
#pragma unroll
  for (int i = 0; i < 4; i++)
#pragma unroll
    for (int j = 0; j < 2; j++)
#pragma unroll
      for (int r = 0; r < 4; r++) {
        int grow = wm * 64 + i * 16 + gq * 4 + r;
        int gcol = n0 + wn * 32 + j * 16 + lr;
        if (m0 + grow < ce) {
          float v = acc[i][j][r];
          float g3 = acc2[i][j][r];
          float sg = v / (1.f + __expf(-v));
          Gout[(size_t)(gbase + m0 + grow) * 2048 + gcol] = f2bf(sg * g3);
        }
      }
}

// ---------------- fused RMSNorm + router logits (MoE pre-norm), NO atomics ----------------
__global__ __launch_bounds__(256) void rmsnorm_router_kernel(
    const float* __restrict__ x, const float* __restrict__ wgt,
    const float* __restrict__ gw, unsigned short* __restrict__ ohi,
    int* __restrict__ selE, float* __restrict__ selW) {
  int row = blockIdx.x;
  const float* xr = x + (size_t)row * H;
  int tid = threadIdx.x;
  float v[4];
  float ss = 0.f;
#pragma unroll
  for (int i = 0; i < 4; i++) {
    v[i] = xr[tid + i * 256];
    ss += v[i] * v[i];
  }
#pragma unroll
  for (int off = 1; off < 64; off <<= 1) ss += __shfl_xor(ss, off);
  __shared__ float part[4];
  __shared__ float red[4][NE];
  if ((tid & 63) == 0) part[tid >> 6] = ss;
  __syncthreads();
  float tot = part[0] + part[1] + part[2] + part[3];
  float r = rsqrtf(tot * (1.f / H) + 1e-6f);
  float acc[NE];
#pragma unroll
  for (int e = 0; e < NE; e++) acc[e] = 0.f;
#pragma unroll
  for (int i = 0; i < 4; i++) {
    int c = tid + i * 256;
    float vv = v[i] * r * wgt[c];
    ohi[(size_t)row * H + c] = f2bf(vv);
    const float4* gp = (const float4*)(gw + (size_t)c * NE);
    float4 g0 = gp[0], g1 = gp[1];
    acc[0] += vv * g0.x;
    acc[1] += vv * g0.y;
    acc[2] += vv * g0.z;
    acc[3] += vv * g0.w;
    acc[4] += vv * g1.x;
    acc[5] += vv * g1.y;
    acc[6] += vv * g1.z;
    acc[7] += vv * g1.w;
  }
#pragma unroll
  for (int off = 1; off < 64; off <<= 1) {
#pragma unroll
    for (int e = 0; e < NE; e++) acc[e] += __shfl_xor(acc[e], off);
  }
  if ((tid & 63) == 0) {
#pragma unroll
    for (int e = 0; e < NE; e++) red[tid >> 6][e] = acc[e];
  }
  __syncthreads();
  if (tid == 0) {
    float lg[NE];
#pragma unroll
    for (int e = 0; e < NE; e++) lg[e] = red[0][e] + red[1][e] + red[2][e] + red[3][e];
    int e1 = 0;
#pragma unroll
    for (int e = 1; e < NE; e++)
      if (lg[e] > lg[e1]) e1 = e;
    int e2 = -1;
#pragma unroll
    for (int e = 0; e < NE; e++)
      if (e != e1 && (e2 < 0 || lg[e] > lg[e2])) e2 = e;
    float w1v = 1.f / (1.f + __expf(lg[e2] - lg[e1]));
    selE[row] = e1 | (e2 << 8);
    selW[row * 2] = w1v;
    selW[row * 2 + 1] = 1.f - w1v;
  }
}

// ---------------- assignment: compacted per-expert lists + per-token slots (one block) ----------------
__global__ __launch_bounds__(256) void assign_kernel(const int* __restrict__ selE,
                                                     int* __restrict__ cnt,
                                                     int* __restrict__ offs,
                                                     int* __restrict__ tmap,
                                                     int* __restrict__ idxb,
                                                     int* __restrict__ tokslot) {
  int tid = threadIdx.x;
  __shared__ int sc[256][NE];
  int pack[8];
  int hist[NE];
#pragma unroll
  for (int e = 0; e < NE; e++) hist[e] = 0;
#pragma unroll
  for (int i = 0; i < 8; i++) {
    pack[i] = selE[tid * 8 + i];
    hist[pack[i] & 255]++;
    hist[(pack[i] >> 8) & 255]++;
  }
#pragma unroll
  for (int e = 0; e < NE; e++) sc[tid][e] = hist[e];
  __syncthreads();
  for (int off = 1; off < 256; off <<= 1) {
    int add[NE];
    bool has = tid >= off;
    if (has) {
#pragma unroll
      for (int e = 0; e < NE; e++) add[e] = sc[tid - off][e];
    }
    __syncthreads();
    if (has) {
#pragma unroll
      for (int e = 0; e < NE; e++) sc[tid][e] += add[e];
    }
    __syncthreads();
  }
  int offsL[NE];
  {
    int a = 0;
#pragma unroll
    for (int e = 0; e < NE; e++) {
      offsL[e] = a;
      a += sc[255][e];
    }
  }
  if (tid == 0) {
    int t = 0;
    for (int e = 0; e < NE; e++) {
      int totE = sc[255][e];
      offs[e] = offsL[e];
      cnt[e] = totE;
      int nt = (totE + 127) >> 7;
      for (int i = 0; i < nt; i++) tmap[t++] = (e << 16) | i;
    }
    offs[NE] = offsL[NE - 1] + sc[255][NE - 1];
    tmap[63] = t;  // t <= 40
  }
  int run[NE];
#pragma unroll
  for (int e = 0; e < NE; e++) run[e] = sc[tid][e] - hist[e];
#pragma unroll
  for (int i = 0; i < 8; i++) {
    int tok = tid * 8 + i;
    int e1 = pack[i] & 255, e2 = (pack[i] >> 8) & 255;
    int p1 = run[e1]++;
    idxb[e1 * S + p1] = tok;
    int p2 = run[e2]++;
    idxb[e2 * S + p2] = tok;
    tokslot[tok * 2] = offsL[e1] + p1;
    tokslot[tok * 2 + 1] = offsL[e2] + p2;
  }
}

// ---------------- gather: out[tok] += w0*(P0+P1)[slot0] + w1*(P0+P1)[slot1] ----------------
__global__ __launch_bounds__(256) void moe_gather_kernel(const float* __restrict__ moeP,
                                                         const int* __restrict__ tokslot,
                                                         const float* __restrict__ selW,
                                                         float* __restrict__ out) {
  int tok = blockIdx.x;
  int c = threadIdx.x * 4;
  int s0 = tokslot[tok * 2], s1 = tokslot[tok * 2 + 1];
  float w0 = selW[tok * 2], w1 = selW[tok * 2 + 1];
  const float* P0 = moeP;
  const float* P1 = moeP + (size_t)4096 * 1024;
  float4 a0 = *(const float4*)(P0 + (size_t)s0 * 1024 + c);
  float4 b0 = *(const float4*)(P1 + (size_t)s0 * 1024 + c);
  float4 a1 = *(const float4*)(P0 + (size_t)s1 * 1024 + c);
  float4 b1 = *(const float4*)(P1 + (size_t)s1 * 1024 + c);
  float* op = out + (size_t)tok * 1024 + c;
  float4 o = *(float4*)op;
  o.x += w0 * (a0.x + b0.x) + w1 * (a1.x + b1.x);
  o.y += w0 * (a0.y + b0.y) + w1 * (a1.y + b1.y);
  o.z += w0 * (a0.z + b0.z) + w1 * (a1.z + b1.z);
  o.w += w0 * (a0.w + b0.w) + w1 * (a1.w + b1.w);
  *(float4*)op = o;
}

// ---------------- MFMA GEMM, BMx64 tile, BK=64, gload_lds + XOR swizzle ----------------
// MODE 0: QKV (BM=64); MODE 3: MOEB (BM=128, K-split x2 -> moeP)
template <int MODE>
__global__ __launch_bounds__(256, 4) void gemm_kernel(
    const unsigned short* __restrict__ Ah, const unsigned short* __restrict__ Al,
    const unsigned short* __restrict__ Bh, const unsigned short* __restrict__ Bl,
    float* __restrict__ C, unsigned short* __restrict__ Gout,
    const int* __restrict__ idx, const int* __restrict__ cnt, const int* __restrict__ offs,
    const int* __restrict__ tmap, int N, int K) {
  constexpr int BM = (MODE <= 1) ? 64 : 128;
  constexpr int NI = BM / 32;
  int n0 = blockIdx.x * 64, m0, e = 0;
  int ce = 0, gbase = 0;
  if (MODE >= 2) {
    int ntiles = tmap[63];
    if ((int)blockIdx.y >= ntiles) return;
    int packed = tmap[blockIdx.y];
    e = packed >> 16;
    m0 = (packed & 0xffff) * 128;
    ce = cnt[e];
    gbase = offs[e];
  } else {
    m0 = blockIdx.y * BM;
  }
  const unsigned short* bhp = Bh;
  const unsigned short* blp = Bl;
  if (MODE == 3) bhp += (size_t)e * 1024 * 2048;

  __shared__ __align__(16) unsigned short tAh[BM * 64];
  __shared__ __align__(16) unsigned short tAl[MODE <= 1 ? BM * 64 : 8];
  __shared__ __align__(16) unsigned short tBh[64 * 64];
  __shared__ __align__(16) unsigned short tBl[MODE <= 2 ? 64 * 64 : 8];

  int tid = threadIdx.x, w = tid >> 6, lane = tid & 63;
  int lr = lane & 15, g = lane >> 4;
  int rloc = lane >> 3, slotg = (lane & 7) ^ rloc;
  int wm = w >> 1, wn = w & 1;

  unsigned aOff[NI], bOff[2];
#pragma unroll
  for (int cc = 0; cc < NI; cc++) {
    int rr = (w * NI + cc) * 8 + rloc;
    if (MODE == 3) {
      int gr = gbase + m0 + rr;
      if (gr > 4095) gr = 4095;
      aOff[cc] = (unsigned)(gr * K + slotg * 8);
    } else {
      aOff[cc] = (unsigned)((m0 + rr) * K + slotg * 8);
    }
  }
#pragma unroll
  for (int cc = 0; cc < 2; cc++) {
    int rr = (w * 2 + cc) * 8 + rloc;
    bOff[cc] = (unsigned)((n0 + rr) * K + slotg * 8);
  }

  f32x4 acc[NI][2];
#pragma unroll
  for (int i = 0; i < NI; i++)
#pragma unroll
    for (int j = 0; j < 2; j++) acc[i][j] = f32x4{0.f, 0.f, 0.f, 0.f};

  int kbeg = 0, kend = K;
  if (MODE == 3) {
    kbeg = (int)blockIdx.z * (K >> 1);
    kend = kbeg + (K >> 1);
  }
  for (int k0 = kbeg; k0 < kend; k0 += 64) {
    __syncthreads();
#pragma unroll
    for (int cc = 0; cc < NI; cc++) {
      int cb = (w * NI + cc) * 512;
      gload16(Ah + aOff[cc] + k0, &tAh[cb]);
      if (MODE <= 1) gload16(Al + aOff[cc] + k0, &tAl[cb]);
    }
#pragma unroll
    for (int cc = 0; cc < 2; cc++) {
      int cb = (w * 2 + cc) * 512;
      gload16(bhp + bOff[cc] + k0, &tBh[cb]);
      if (MODE <= 2) gload16(blp + bOff[cc] + k0, &tBl[cb]);
    }
    __syncthreads();
    bf16x8 fah[NI][2], fal[NI][2];
#pragma unroll
    for (int i = 0; i < NI; i++) {
      int ar = wm * (BM / 2) + i * 16 + lr;
#pragma unroll
      for (int kk = 0; kk < 2; kk++) {
        int off = ar * 64 + (((kk * 4 + g) ^ (ar & 7)) * 8);
        fah[i][kk] = *(const bf16x8*)&tAh[off];
        if (MODE <= 1) fal[i][kk] = *(const bf16x8*)&tAl[off];
      }
    }
#pragma unroll
    for (int j = 0; j < 2; j++) {
      int br = wn * 32 + j * 16 + lr;
      bf16x8 fbh[2], fbl[2];
#pragma unroll
      for (int kk = 0; kk < 2; kk++) {
        int off = br * 64 + (((kk * 4 + g) ^ (br & 7)) * 8);
        fbh[kk] = *(const bf16x8*)&tBh[off];
        if (MODE <= 2) fbl[kk] = *(const bf16x8*)&tBl[off];
      }
#pragma unroll
      for (int i = 0; i < NI; i++) {
#pragma unroll
        for (int kk = 0; kk < 2; kk++) {
          acc[i][j] = __builtin_amdgcn_mfma_f32_16x16x32_bf16(fah[i][kk], fbh[kk], acc[i][j], 0, 0, 0);
          if (MODE <= 1) {
            acc[i][j] = __builtin_amdgcn_mfma_f32_16x16x32_bf16(fah[i][kk], fbl[kk], acc[i][j], 0, 0, 0);
            acc[i][j] = __builtin_amdgcn_mfma_f32_16x16x32_bf16(fal[i][kk], fbh[kk], acc[i][j], 0, 0, 0);
          }
        }
      }
    }
  }
#pragma unroll
  for (int i = 0; i < NI; i++)
#pragma unroll
    for (int j = 0; j < 2; j++)
#pragma unroll
      for (int r = 0; r < 4; r++) {
        int grow = wm * (BM / 2) + i * 16 + g * 4 + r;
        int gcol = n0 + wn * 32 + j * 16 + lr;
        float v = acc[i][j][r];
        if (MODE == 0) {
          C[(size_t)(m0 + grow) * N + gcol] = v;
        } else if (MODE == 3) {
          if (m0 + grow < ce) {
            C[(size_t)blockIdx.z * 4096 * 1024 + (size_t)(gbase + m0 + grow) * 1024 + gcol] = v;
          }
        }
      }
}

// ---------------- flash attention (MFMA, LDS-staged, balanced 1-D grid) ----------------
#define FSWZ(row, byteoff) ((byteoff) ^ (((row) & 7) << 4))

__global__ __launch_bounds__(256, 4) void flash_kernel(
    const unsigned short* __restrict__ qhi, const unsigned short* __restrict__ qlo,
    const unsigned short* __restrict__ khip, const unsigned short* __restrict__ klop,
    const unsigned short* __restrict__ vthip, const unsigned short* __restrict__ vtlop,
    const float* __restrict__ amask, float* __restrict__ po, float* __restrict__ pm,
    float* __restrict__ pl) {
  int u = blockIdx.x;
  int r_ = u >> 8, base = u & 255;
  int qt = (base + r_ * 8) & 31;
  int head = ((base >> 5) & 7) | ((r_ & 1) << 3);
  int z = r_ >> 1;
  int tid = threadIdx.x;
  int w = tid >> 6, lane = tid & 63;
  int lr = lane & 15, g = lane >> 4;
  int rloc = lane >> 3, slotg = (lane & 7) ^ rloc;

  __shared__ __align__(16) unsigned short Khi[64 * 64];
  __shared__ __align__(16) unsigned short Klo[64 * 64];
  __shared__ __align__(16) unsigned short Vhi[64 * 64];
  __shared__ __align__(16) unsigned short Vlo[64 * 64];
  __shared__ __align__(16) unsigned short Pbuf[4][16 * 64];

  int qrow = qt * 64 + w * 16 + lr;
  bf16x8 qh[2], ql[2];
  {
    const unsigned short* qb = qhi + ((size_t)head * S + qrow) * HD;
    const unsigned short* qb2 = qlo + ((size_t)head * S + qrow) * HD;
    qh[0] = *(const bf16x8*)(qb + g * 8);
    qh[1] = *(const bf16x8*)(qb + 32 + g * 8);
    ql[0] = *(const bf16x8*)(qb2 + g * 8);
    ql[1] = *(const bf16x8*)(qb2 + 32 + g * 8);
  }

  f32x4 oacc[4];
#pragma unroll
  for (int dg = 0; dg < 4; dg++) oacc[dg] = f32x4{0.f, 0.f, 0.f, 0.f};
  float m = -1e30f, l = 0.f;

  const unsigned short* kbh = khip + (size_t)(head >> 1) * S * HD;
  const unsigned short* kbl = klop + (size_t)(head >> 1) * S * HD;
  const unsigned short* vbh = vthip + (size_t)(head >> 1) * HD * S;
  const unsigned short* vbl = vtlop + (size_t)(head >> 1) * HD * S;
  char* pbase = (char*)Pbuf[w];

  int nblk = qt + 1;
  int b0 = (z * nblk) >> 1, b1 = ((z + 1) * nblk) >> 1;

  for (int kb = b0; kb < b1; kb++) {
    int kv0 = kb * 64;
    __syncthreads();
#pragma unroll
    for (int cc = 0; cc < 2; cc++) {
      int c = w * 2 + cc;
      int r = c * 8 + rloc;
      gload16(kbh + (size_t)(kv0 + r) * HD + slotg * 8, &Khi[c * 512]);
      gload16(kbl + (size_t)(kv0 + r) * HD + slotg * 8, &Klo[c * 512]);
      gload16(vbh + (size_t)r * S + kv0 + slotg * 8, &Vhi[c * 512]);
      gload16(vbl + (size_t)r * S + kv0 + slotg * 8, &Vlo[c * 512]);
    }
    unsigned long long vm = __ballot(amask[kv0 + lane] > 0.f);
    __syncthreads();

    f32x4 sacc[4];
#pragma unroll
    for (int c = 0; c < 4; c++) sacc[c] = f32x4{0.f, 0.f, 0.f, 0.f};
#pragma unroll
    for (int c = 0; c < 4; c++) {
#pragma unroll
      for (int kc = 0; kc < 2; kc++) {
        int row = c * 16 + lr;
        int bo = FSWZ(row, row * 128 + kc * 64 + g * 16);
        bf16x8 khf = *(const bf16x8*)((char*)Khi + bo);
        bf16x8 klf = *(const bf16x8*)((char*)Klo + bo);
        sacc[c] = __builtin_amdgcn_mfma_f32_16x16x32_bf16(khf, qh[kc], sacc[c], 0, 0, 0);
        sacc[c] = __builtin_amdgcn_mfma_f32_16x16x32_bf16(khf, ql[kc], sacc[c], 0, 0, 0);
        sacc[c] = __builtin_amdgcn_mfma_f32_16x16x32_bf16(klf, qh[kc], sacc[c], 0, 0, 0);
      }
    }
    int qloc = w * 16 + lr;
    bool diag = (kb == qt);
    bool fullvis = (vm == ~0ull) && !diag;
    float tm = -1e30f;
    if (fullvis) {
#pragma unroll
      for (int c = 0; c < 4; c++)
#pragma unroll
        for (int r = 0; r < 4; r++) tm = fmaxf(tm, sacc[c][r]);
    } else {
#pragma unroll
      for (int c = 0; c < 4; c++) {
#pragma unroll
        for (int r = 0; r < 4; r++) {
          int kvloc = c * 16 + 4 * g + r;
          bool vis = ((vm >> kvloc) & 1ull) && (!diag || kvloc <= qloc);
          float sv = vis ? sacc[c][r] : -1e30f;
          sacc[c][r] = sv;
          tm = fmaxf(tm, sv);
        }
      }
    }
    tm = fmaxf(tm, __shfl_xor(tm, 16));
    tm = fmaxf(tm, __shfl_xor(tm, 32));
    bool skip = __all(tm - m <= 8.f);
    float newm = skip ? m : fmaxf(m, tm);
    float rs = 0.f;
#pragma unroll
    for (int c = 0; c < 4; c++) {
#pragma unroll
      for (int r = 0; r < 4; r++) {
        float p = __expf(sacc[c][r] - newm);
        sacc[c][r] = p;
        rs += p;
      }
    }
    rs += __shfl_xor(rs, 16);
    rs += __shfl_xor(rs, 32);
    if (!skip) {
      float alpha = __expf(m - newm);
      m = newm;
      l = l * alpha + rs;
#pragma unroll
      for (int dg = 0; dg < 4; dg++) {
#pragma unroll
        for (int r = 0; r < 4; r++) oacc[dg][r] *= alpha;
      }
    } else {
      l += rs;
    }
    unsigned hw[4][2];
#pragma unroll
    for (int c = 0; c < 4; c++) {
      hw[c][0] = cvtpk(sacc[c][0], sacc[c][1]);
      hw[c][1] = cvtpk(sacc[c][2], sacc[c][3]);
      uint2 hv = {hw[c][0], hw[c][1]};
      *(uint2*)(pbase + FSWZ(lr, lr * 128 + (c * 16 + 4 * g) * 2)) = hv;
    }
    bf16x8 pbh[2], pbl[2];
#pragma unroll
    for (int kc = 0; kc < 2; kc++)
      pbh[kc] = *(const bf16x8*)(pbase + FSWZ(lr, lr * 128 + kc * 64 + g * 16));
#pragma unroll
    for (int c = 0; c < 4; c++) {
      float h0 = __builtin_bit_cast(float, hw[c][0] << 16);
      float h1 = __builtin_bit_cast(float, hw[c][0] & 0xffff0000u);
      float h2 = __builtin_bit_cast(float, hw[c][1] << 16);
      float h3 = __builtin_bit_cast(float, hw[c][1] & 0xffff0000u);
      uint2 lv = {cvtpk(sacc[c][0] - h0, sacc[c][1] - h1),
                  cvtpk(sacc[c][2] - h2, sacc[c][3] - h3)};
      *(uint2*)(pbase + FSWZ(lr, lr * 128 + (c * 16 + 4 * g) * 2)) = lv;
    }
#pragma unroll
    for (int kc = 0; kc < 2; kc++)
      pbl[kc] = *(const bf16x8*)(pbase + FSWZ(lr, lr * 128 + kc * 64 + g * 16));
#pragma unroll
    for (int dg = 0; dg < 4; dg++) {
#pragma unroll
      for (int kc = 0; kc < 2; kc++) {
        int row = dg * 16 + lr;
        int bo = FSWZ(row, row * 128 + kc * 64 + g * 16);
        bf16x8 vhf = *(const bf16x8*)((char*)Vhi + bo);
        bf16x8 vlf = *(const bf16x8*)((char*)Vlo + bo);
        oacc[dg] = __builtin_amdgcn_mfma_f32_16x16x32_bf16(vhf, pbh[kc], oacc[dg], 0, 0, 0);
        oacc[dg] = __builtin_amdgcn_mfma_f32_16x16x32_bf16(vhf, pbl[kc], oacc[dg], 0, 0, 0);
        oacc[dg] = __builtin_amdgcn_mfma_f32_16x16x32_bf16(vlf, pbh[kc], oacc[dg], 0, 0, 0);
      }
    }
  }

  size_t pb = (size_t)(qt * 16 + head) * 2 + z;
  int row = w * 16 + lr;
  if (g == 0) {
    pm[pb * 64 + row] = m;
    pl[pb * 64 + row] = l;
  }
  float* pob = po + pb * 4096 + (size_t)row * 64;
#pragma unroll
  for (int dg = 0; dg < 4; dg++) {
    float4 v4 = {oacc[dg][0], oacc[dg][1], oacc[dg][2], oacc[dg][3]};
    *(float4*)(pob + dg * 16 + 4 * g) = v4;
  }
}

// merge 2 kv-split partials -> o hi/lo bf16 planes
__global__ __launch_bounds__(256) void combine_kernel(const float* __restrict__ po,
                                                      const float* __restrict__ pm,
                                                      const float* __restrict__ pl,
                                                      unsigned short* __restrict__ ohi,
                                                      unsigned short* __restrict__ olo) {
  int qt = blockIdx.x, head = blockIdx.y;
  int r = threadIdx.x >> 2, dg = (threadIdx.x & 3) * 16;
  size_t base = (size_t)(qt * 16 + head) * 2;
  float m0v = pm[base * 64 + r], m1v = pm[(base + 1) * 64 + r];
  float l0 = pl[base * 64 + r], l1 = pl[(base + 1) * 64 + r];
  float M = fmaxf(m0v, m1v);
  float w0 = __expf(m0v - M), w1 = __expf(m1v - M);
  float inv = 1.f / (w0 * l0 + w1 * l1);
  const float* p0 = po + base * 4096 + (size_t)r * 64 + dg;
  const float* p1 = po + (base + 1) * 4096 + (size_t)r * 64 + dg;
  unsigned short th[16], tl[16];
#pragma unroll
  for (int i = 0; i < 16; i += 4) {
    float4 a = *(const float4*)(p0 + i);
    float4 b = *(const float4*)(p1 + i);
    float vv[4] = {(w0 * a.x + w1 * b.x) * inv, (w0 * a.y + w1 * b.y) * inv,
                   (w0 * a.z + w1 * b.z) * inv, (w0 * a.w + w1 * b.w) * inv};
#pragma unroll
    for (int j = 0; j < 4; j++) {
      unsigned short h_ = f2bf(vv[j]);
      th[i + j] = h_;
      tl[i + j] = f2bf(vv[j] - bf2f(h_));
    }
  }
  size_t ob = (size_t)(qt * 64 + r) * 1024 + head * 64 + dg;
  *(bf16x8*)(ohi + ob) = *(bf16x8*)&th[0];
  *(bf16x8*)(ohi + ob + 8) = *(bf16x8*)&th[8];
  *(bf16x8*)(olo + ob) = *(bf16x8*)&tl[0];
  *(bf16x8*)(olo + ob + 8) = *(bf16x8*)&tl[8];
}

// ---------------- launch ----------------
extern "C" void kernel_launch(void* const* d_in, const int* in_sizes, int n_in,
                              void* d_out, int out_size, void* d_ws, size_t ws_size,
                              hipStream_t stream) {
  const float* x = (const float*)d_in[0];
  const float* amask = (const float*)d_in[1];
  const int* pos = (const int*)d_in[2];
  const float* sinb = (const float*)d_in[3];
  const float* cosb = (const float*)d_in[4];
  const float* wq = (const float*)d_in[5];
  const float* wk = (const float*)d_in[6];
  const float* wv = (const float*)d_in[7];
  const float* wo = (const float*)d_in[8];
  const float* ln1 = (const float*)d_in[9];
  const float* ln2 = (const float*)d_in[10];
  const float* gw = (const float*)d_in[11];
  const float* w1 = (const float*)d_in[12];
  const float* w3 = (const float*)d_in[13];
  const float* w2 = (const float*)d_in[14];
  float* out = (float*)d_out;

  char* ws = (char*)d_ws;
  const size_t MB = 1024 * 1024;
  // persistent (R21 layout; w2T moved to 97-129 so it can be built concurrent with gemm2)
  float* x2 = (float*)(ws + 0 * MB);                      // 0-8
  unsigned short* t_bf = (unsigned short*)(ws + 8 * MB);  // 8-12
  int* cnt = (int*)(ws + 12 * MB);                        // 12-13 small arrays
  int* offs = cnt + 16;
  int* tmap = cnt + 32;
  int* idxb = cnt + 128;
  int* selE = idxb + 16384;
  int* tokslot = selE + 2048;
  float* selW = (float*)(tokslot + 4096);
  // o planes (combine -> gemm1); G overlays after (gemm2 -> gemm3)
  unsigned short* o_hi = (unsigned short*)(ws + 13 * MB);  // 13-17
  unsigned short* o_lo = (unsigned short*)(ws + 17 * MB);  // 17-21
  unsigned short* G = (unsigned short*)(ws + 13 * MB);     // 13-29 (after o dead)
  float* qkv = (float*)(ws + 13 * MB);                     // 13-29 (dead before combine)
  // w1T/w3T (merged gemm1_w13 -> gemm2); moeP overlays w3T after gemm2
  unsigned short* w1T = (unsigned short*)(ws + 29 * MB);  // 29-61
  unsigned short* w3T = (unsigned short*)(ws + 61 * MB);  // 61-93
  float* moeP = (float*)(ws + 61 * MB);                   // gemm3+ (w3T dead)
  // overlays inside 29-93, all dead before merged gemm1+w13 kernel:
  float* po = (float*)(ws + 29 * MB);                          // 29-45 (flash->combine)
  float* pm = (float*)(ws + 45 * MB);                          // 0.25 MB
  float* pl = (float*)(ws + 46 * MB);                          // 0.25 MB
  unsigned short* wqkvT_hi = (unsigned short*)(ws + 47 * MB);  // 47-51
  unsigned short* wqkvT_lo = (unsigned short*)(ws + 51 * MB);  // 51-55
  unsigned short* h_hi = (unsigned short*)(ws + 55 * MB);      // 55-59
  unsigned short* h_lo = (unsigned short*)(ws + 59 * MB);      // 59-63
  unsigned short* q_hi = (unsigned short*)(ws + 63 * MB);      // 63-67
  unsigned short* q_lo = (unsigned short*)(ws + 67 * MB);      // 67-71
  unsigned short* k_hi = (unsigned short*)(ws + 71 * MB);      // 71-73
  unsigned short* k_lo = (unsigned short*)(ws + 73 * MB);      // 73-75
  unsigned short* vT_hi = (unsigned short*)(ws + 75 * MB);     // 75-77
  unsigned short* vT_lo = (unsigned short*)(ws + 77 * MB);     // 77-79
  // woT outside 29-93 (live until gemm1)
  unsigned short* woT_hi = (unsigned short*)(ws + 93 * MB);  // 93-95
  unsigned short* woT_lo = (unsigned short*)(ws + 95 * MB);  // 95-97
  // w2T at 97-129 (built during gemm2, read by gemm3; ws>=129MB proven in R22)
  unsigned short* w2T = (unsigned short*)(ws + 97 * MB);  // 97-129

  // attention block
  prep_kernel<<<2432, 256, 0, stream>>>(x, ln1, h_hi, h_lo, wq, wk, wv, wo, wqkvT_hi, wqkvT_lo,
                                        woT_hi, woT_lo);
  gemm_kernel<0><<<dim3(32, 32, 1), 256, 0, stream>>>(h_hi, h_lo, wqkvT_hi, wqkvT_lo, qkv, nullptr,
                                                      nullptr, nullptr, nullptr, nullptr, 2048,
                                                      1024);
  rv_kernel<<<6400, 256, 0, stream>>>(qkv, sinb, cosb, pos, q_hi, q_lo, k_hi, k_lo, vT_hi, vT_lo);
  flash_kernel<<<dim3(1024, 1, 1), 256, 0, stream>>>(q_hi, q_lo, k_hi, k_lo, vT_hi, vT_lo, amask,
                                                     po, pm, pl);
  combine_kernel<<<dim3(32, 16), 256, 0, stream>>>(po, pm, pl, o_hi, o_lo);
  // merged O-proj GEMM + w1/w3 tconv (independent; co-scheduled)
  gemm1_w13_kernel<<<4608, 256, 0, stream>>>(o_hi, o_lo, woT_hi, woT_lo, x2, out, x, w1, w3, w1T,
                                             w3T);
  // MoE block
  rmsnorm_router_kernel<<<S, 256, 0, stream>>>(x2, ln2, gw, t_bf, selE, selW);
  assign_kernel<<<1, 256, 0, stream>>>(selE, cnt, offs, tmap, idxb, tokslot);
  // merged MoE gemm2 + w2 tconv (independent; co-scheduled)
  gemm2_w2_kernel<<<3328, 256, 0, stream>>>(t_bf, w1T, w3T, G, idxb, cnt, offs, tmap, w2, w2T);
  gemm_kernel<3><<<dim3(16, 40, 2), 256, 0, stream>>>(G, nullptr, w2T, nullptr, moeP, nullptr,
                                                      idxb, cnt, offs, tmap, 1024, 2048);
  moe_gather_kernel<<<S, 256, 0, stream>>>(moeP, tokslot, selW, out);
}